// Round 11
// baseline (597.302 us; speedup 1.0000x reference)
//
#include <hip/hip_runtime.h>
#include <cstddef>

#define NN 1024
#define DD 6
#define TT 60
#define HH 64
#define NEGV  (-10000.0f)
#define SLOPEV (0.01f)
#define NTH  576          // 9 waves
#define GRUB 512          // GRU blocks (2 samples each)
#define RELB 455          // rel streaming blocks

typedef _Float16 h2_t __attribute__((ext_vector_type(2)));

__device__ __forceinline__ float sig_(float x)  { return 1.0f / (1.0f + __expf(-x)); }
__device__ __forceinline__ float tanh_(float x) { return 1.0f - 2.0f / (__expf(2.0f * x) + 1.0f); }
__device__ __forceinline__ float rl_(float v, int l) {
    return __int_as_float(__builtin_amdgcn_readlane(__float_as_int(v), l));
}
__device__ __forceinline__ h2_t bch2_(float v) { return __builtin_bit_cast(h2_t, v); }
// pack h pair (lane, lane^32) for the dot2 weight layout (j, j+32)
__device__ __forceinline__ float packh_(float hnew) {
    const float other = __shfl_xor(hnew, 32);
    return __builtin_bit_cast(float, __builtin_amdgcn_cvt_pkrtz(hnew, other));
}
// pack weight row pairs (j, j+32): wp[j] = (Wrow[j], Wrow[j+32]), j<32
__device__ __forceinline__ void packw_(const float* __restrict__ Wrow, float* wp) {
    #pragma unroll
    for (int j = 0; j < 32; ++j)
        wp[j] = __builtin_bit_cast(float, __builtin_amdgcn_cvt_pkrtz(Wrow[j], Wrow[j + 32]));
}

__device__ __forceinline__ void rel_pair(const float* __restrict__ rel,
                                         const float* __restrict__ Wv,
                                         float* __restrict__ sr,
                                         float* __restrict__ ssum,
                                         unsigned int relp)
{
    const float4* base = (const float4*)(rel + (size_t)relp * 64);
    float d0 = 0.f, d1 = 0.f, s0 = 0.f, s1 = 0.f;
    #pragma unroll
    for (int c = 0; c < 2; ++c) {
        float4 v[8];
        #pragma unroll
        for (int q = 0; q < 8; ++q) v[q] = base[c * 8 + q];   // 8 loads in flight
        #pragma unroll
        for (int q = 0; q < 8; ++q) {
            const float4 wq = ((const float4*)Wv)[c * 8 + q];
            d0 += v[q].x * wq.x + v[q].z * wq.z;
            d1 += v[q].y * wq.y + v[q].w * wq.w;
            s0 += v[q].x + v[q].z;
            s1 += v[q].y + v[q].w;
        }
    }
    sr[relp]   = d0 + d1;
    ssum[relp] = s0 + s1;
}

// ---------------------------------------------------------------------------
// k_main: heterogeneous BLOCKS — GRU blocks carry no HBM latency in their
// barrier cohort; rel blocks have no barriers at all.
//   blocks [0,512)   : GRU, 9 waves, 2 samples. waves 0-2 = L0 gate g
//                      (x(12)+Wih0(6)+packed Whh0(32) in regs); waves 3-8 =
//                      L1 (gate g, matrix m), packed row(32). f16 dot2 MM
//                      (fp32 acc), h bcast via readlane of (j,j+32)-packed
//                      pairs; ONE barrier/step, parity double-buffered LDS,
//                      redundant activations; pack = single shfl_xor(32).
//   blocks [512,967) : rel streaming, grid-stride 1 pair/thread/iter.
// R10 bug fixed: sample-1 accumulator chains (a1) were initialized to 0,
// dropping bhh0 / b(ih|hh)1 — now start at the bias like a0.
// ---------------------------------------------------------------------------
__global__ __launch_bounds__(NTH)
void k_main(const float* __restrict__ x, const float* __restrict__ rel,
            const float* __restrict__ W, const float* __restrict__ fc_w,
            const float* __restrict__ Wih0, const float* __restrict__ Whh0,
            const float* __restrict__ bih0, const float* __restrict__ bhh0,
            const float* __restrict__ Wih1, const float* __restrict__ Whh1,
            const float* __restrict__ bih1, const float* __restrict__ bhh1,
            float* __restrict__ sa, float* __restrict__ sb,
            float* __restrict__ hdot, float* __restrict__ hb,
            float* __restrict__ sr, float* __restrict__ ssum)
{
    __shared__ float smem[2624];
    // GRU: L0B[par][g(4)][s(2)][64] -> [0,1024); L1B[par][g(3)][m(2)][s(2)][64]
    //      -> [1024,2560).  Rel blocks: Wv[64] at [2560,2624).
    float* L0B = smem;
    float* L1B = smem + 1024;
    float* Wv  = smem + 2560;

    const int tid  = threadIdx.x;

    if (blockIdx.x >= GRUB) {
        // ---------------- relation streaming (no barriers in loop) ----------
        if (tid < 64) Wv[tid] = W[2 * HH + tid];
        __syncthreads();
        const unsigned base = (unsigned)(blockIdx.x - GRUB) * NTH + tid;
        for (unsigned p = base; p < (unsigned)(NN * NN); p += (unsigned)RELB * NTH)
            rel_pair(rel, Wv, sr, ssum, p);
        return;
    }

    // ---------------- GRU ----------------
    const int wv   = tid >> 6;
    const int lane = tid & 63;
    const int nb   = blockIdx.x * 2;

    float wreg[50];
    float hr2[2];            // packed (lane j: h[j],h[j+32]) pairs, lanes 0..31
    float hrf[2];            // f32 state at row = lane
    float b0 = 0.f, b1 = 0.f;
    int m1 = 0;

    hr2[0] = hr2[1] = 0.f;
    hrf[0] = hrf[1] = 0.f;

    if (wv < 3) {
        const int row = wv * 64 + lane;
        #pragma unroll
        for (int s = 0; s < 2; ++s)
            #pragma unroll
            for (int d = 0; d < DD; ++d)
                wreg[s * 6 + d] = (lane < TT) ? x[(size_t)(nb + s) * DD * TT + d * TT + lane] : 0.f;
        #pragma unroll
        for (int d = 0; d < DD; ++d) wreg[12 + d] = Wih0[row * DD + d];
        float wrow[64];
        #pragma unroll
        for (int q = 0; q < 16; ++q) {
            const float4 v = *(const float4*)(Whh0 + (size_t)row * HH + q * 4);
            wrow[4*q] = v.x; wrow[4*q+1] = v.y; wrow[4*q+2] = v.z; wrow[4*q+3] = v.w;
        }
        packw_(wrow, wreg + 18);
        b0 = bih0[row]; b1 = bhh0[row];
    } else {
        const int u = wv - 3;
        m1 = u & 1;
        const int row = (u >> 1) * 64 + lane;
        const float* Wm = m1 ? Whh1 : Wih1;
        float wrow[64];
        #pragma unroll
        for (int q = 0; q < 16; ++q) {
            const float4 v = *(const float4*)(Wm + (size_t)row * HH + q * 4);
            wrow[4*q] = v.x; wrow[4*q+1] = v.y; wrow[4*q+2] = v.z; wrow[4*q+3] = v.w;
        }
        packw_(wrow, wreg);
        b0 = m1 ? bhh1[row] : bih1[row];
    }
    __syncthreads();

    for (int i = 0; i <= TT; ++i) {
        const int par = i & 1;

        // ---------------- MM phase ----------------
        if (wv < 3) {
            if (i < TT) {
                float xg0 = b0, xg1 = b0;
                #pragma unroll
                for (int d = 0; d < DD; ++d) {
                    const float wd = wreg[12 + d];
                    xg0 += rl_(wreg[d], i) * wd;
                    xg1 += rl_(wreg[6 + d], i) * wd;
                }
                float a0 = b1, c0 = 0.f, a1 = b1, c1 = 0.f;   // split chains (a1 = b1: R10 fix)
                #pragma unroll
                for (int j = 0; j < 16; ++j) {
                    const h2_t wj = bch2_(wreg[18 + j]);
                    const h2_t wk = bch2_(wreg[34 + j]);
                    a0 = __builtin_amdgcn_fdot2(bch2_(rl_(hr2[0], j)),      wj, a0, false);
                    c0 = __builtin_amdgcn_fdot2(bch2_(rl_(hr2[0], 16 + j)), wk, c0, false);
                    a1 = __builtin_amdgcn_fdot2(bch2_(rl_(hr2[1], j)),      wj, a1, false);
                    c1 = __builtin_amdgcn_fdot2(bch2_(rl_(hr2[1], 16 + j)), wk, c1, false);
                }
                const float hg0 = a0 + c0, hg1 = a1 + c1;
                if (wv < 2) {
                    L0B[((par * 4 + wv) * 2 + 0) * 64 + lane] = xg0 + hg0;
                    L0B[((par * 4 + wv) * 2 + 1) * 64 + lane] = xg1 + hg1;
                } else {
                    L0B[((par * 4 + 2) * 2 + 0) * 64 + lane] = xg0;
                    L0B[((par * 4 + 2) * 2 + 1) * 64 + lane] = xg1;
                    L0B[((par * 4 + 3) * 2 + 0) * 64 + lane] = hg0;
                    L0B[((par * 4 + 3) * 2 + 1) * 64 + lane] = hg1;
                }
            }
        } else {
            if (i >= 1) {
                const int u = wv - 3, g = u >> 1;
                float a0 = b0, c0 = 0.f, a1 = b0, c1 = 0.f;   // a1 = b0: R10 fix
                #pragma unroll
                for (int j = 0; j < 16; ++j) {
                    const h2_t wj = bch2_(wreg[j]);
                    const h2_t wk = bch2_(wreg[16 + j]);
                    a0 = __builtin_amdgcn_fdot2(bch2_(rl_(hr2[0], j)),      wj, a0, false);
                    c0 = __builtin_amdgcn_fdot2(bch2_(rl_(hr2[0], 16 + j)), wk, c0, false);
                    a1 = __builtin_amdgcn_fdot2(bch2_(rl_(hr2[1], j)),      wj, a1, false);
                    c1 = __builtin_amdgcn_fdot2(bch2_(rl_(hr2[1], 16 + j)), wk, c1, false);
                }
                L1B[(((par * 3 + g) * 2 + m1) * 2 + 0) * 64 + lane] = a0 + c0;
                L1B[(((par * 3 + g) * 2 + m1) * 2 + 1) * 64 + lane] = a1 + c1;
            }
        }
        __syncthreads();

        // ---------------- redundant activations (no 2nd barrier) ------------
        const bool needs_h0 = (wv < 3) || (m1 == 0);
        if (needs_h0 && i < TT) {
            #pragma unroll
            for (int s = 0; s < 2; ++s) {
                const float r  = sig_(L0B[((par * 4 + 0) * 2 + s) * 64 + lane]);
                const float z  = sig_(L0B[((par * 4 + 1) * 2 + s) * 64 + lane]);
                const float xn = L0B[((par * 4 + 2) * 2 + s) * 64 + lane];
                const float hn = L0B[((par * 4 + 3) * 2 + s) * 64 + lane];
                const float nv = tanh_(xn + r * hn);
                const float hnew = (1.f - z) * nv + z * hrf[s];
                hrf[s] = hnew;
                hr2[s] = packh_(hnew);
            }
        } else if (!needs_h0 && i >= 1) {          // m1==1 waves track h1
            #pragma unroll
            for (int s = 0; s < 2; ++s) {
                const float r1 = sig_(L1B[(((par * 3 + 0) * 2 + 0) * 2 + s) * 64 + lane]
                                    + L1B[(((par * 3 + 0) * 2 + 1) * 2 + s) * 64 + lane]);
                const float z1 = sig_(L1B[(((par * 3 + 1) * 2 + 0) * 2 + s) * 64 + lane]
                                    + L1B[(((par * 3 + 1) * 2 + 1) * 2 + s) * 64 + lane]);
                const float xn1 = L1B[(((par * 3 + 2) * 2 + 0) * 2 + s) * 64 + lane];
                const float hn1 = L1B[(((par * 3 + 2) * 2 + 1) * 2 + s) * 64 + lane];
                const float nv1 = tanh_(xn1 + r1 * hn1);
                const float hnew = (1.f - z1) * nv1 + z1 * hrf[s];
                hrf[s] = hnew;
                hr2[s] = packh_(hnew);
            }
        }
    }

    // ---------------- epilogue: wave 4 (g=0,m=1) holds final h1 f32 ---------
    if (wv == 4) {
        #pragma unroll
        for (int s = 0; s < 2; ++s) {
            const float hv = hrf[s];
            float pa = hv * W[lane];
            float pb = hv * W[HH + lane];
            float pc = hv * fc_w[lane];
            float pd = hv * fc_w[HH + lane];
            #pragma unroll
            for (int off = 32; off >= 1; off >>= 1) {
                pa += __shfl_down(pa, off);
                pb += __shfl_down(pb, off);
                pc += __shfl_down(pc, off);
                pd += __shfl_down(pd, off);
            }
            if (lane == 0) {
                sa[nb + s] = pa; sb[nb + s] = pb;
                hdot[nb + s] = pc; hb[nb + s] = pd;
            }
        }
    }
}

// ---------------------------------------------------------------------------
// k2: per row i — masked leaky scores, exact masked-softmax semantics,
// out_i = hdot_i + (sum_j e_j*m_j*hb_j)/denom + fc_b.
// ---------------------------------------------------------------------------
__global__ __launch_bounds__(256)
void k2(const float* __restrict__ sa, const float* __restrict__ sb,
        const float* __restrict__ hdot, const float* __restrict__ hb,
        const float* __restrict__ sr, const float* __restrict__ ssum,
        const float* __restrict__ bscal, const float* __restrict__ fc_b,
        float* __restrict__ out)
{
    __shared__ float red[12];
    const int i   = blockIdx.x;
    const int tid = threadIdx.x;
    const int j4  = tid * 4;
    const float sai = sa[i] + bscal[0];

    const float4 srv = *(const float4*)(sr   + (size_t)i * NN + j4);
    const float4 ssv = *(const float4*)(ssum + (size_t)i * NN + j4);
    const float4 sbv = *(const float4*)(sb + j4);

    float tv[4], mk[4];
    float mloc = -3.4e38f;
    {
        const float srq[4] = {srv.x, srv.y, srv.z, srv.w};
        const float ssq[4] = {ssv.x, ssv.y, ssv.z, ssv.w};
        const float sbq[4] = {sbv.x, sbv.y, sbv.z, sbv.w};
        #pragma unroll
        for (int q = 0; q < 4; ++q) {
            float w = sai + sbq[q] + srq[q];
            w = (w >= 0.0f) ? w : SLOPEV * w;
            const float m = (ssq[q] != 0.0f) ? 1.0f : 0.0f;
            float t = m * w;
            t = (t == 0.0f) ? NEGV : t;
            tv[q] = t; mk[q] = m;
            mloc = fmaxf(mloc, t);
        }
    }
    #pragma unroll
    for (int off = 32; off >= 1; off >>= 1) mloc = fmaxf(mloc, __shfl_xor(mloc, off));
    if ((tid & 63) == 0) red[tid >> 6] = mloc;
    __syncthreads();
    const float mx = fmaxf(fmaxf(red[0], red[1]), fmaxf(red[2], red[3]));

    const float4 hbv = *(const float4*)(hb + j4);
    const float hbq[4] = {hbv.x, hbv.y, hbv.z, hbv.w};
    float sloc = 0.0f, vloc = 0.0f;
    #pragma unroll
    for (int q = 0; q < 4; ++q) {
        const float e = __expf(tv[q] - mx);   // masked -> exp(-1e4 - mx) == 0
        sloc += e;
        vloc += e * mk[q] * hbq[q];
    }
    #pragma unroll
    for (int off = 32; off >= 1; off >>= 1) {
        sloc += __shfl_xor(sloc, off);
        vloc += __shfl_xor(vloc, off);
    }
    if ((tid & 63) == 0) { red[4 + (tid >> 6)] = sloc; red[8 + (tid >> 6)] = vloc; }
    __syncthreads();
    if (tid == 0) {
        const float denom = red[4] + red[5] + red[6] + red[7];
        const float vsum  = red[8] + red[9] + red[10] + red[11];
        out[i] = hdot[i] + vsum / denom + fc_b[0];
    }
}

// ---------------------------------------------------------------------------
extern "C" void kernel_launch(void* const* d_in, const int* in_sizes, int n_in,
                              void* d_out, int out_size, void* d_ws, size_t ws_size,
                              hipStream_t stream)
{
    const float* x     = (const float*)d_in[0];
    const float* rel   = (const float*)d_in[1];
    const float* W     = (const float*)d_in[2];
    const float* b     = (const float*)d_in[3];
    const float* fc_w  = (const float*)d_in[4];
    const float* fc_b  = (const float*)d_in[5];
    const float* Wih0  = (const float*)d_in[6];
    const float* Whh0  = (const float*)d_in[7];
    const float* bih0  = (const float*)d_in[8];
    const float* bhh0  = (const float*)d_in[9];
    const float* Wih1  = (const float*)d_in[10];
    const float* Whh1  = (const float*)d_in[11];
    const float* bih1  = (const float*)d_in[12];
    const float* bhh1  = (const float*)d_in[13];

    float* ws   = (float*)d_ws;
    float* sa   = ws;                         // 1024
    float* sb   = sa   + NN;                  // 1024
    float* hdot = sb   + NN;                  // 1024
    float* hb   = hdot + NN;                  // 1024
    float* sr   = hb   + NN;                  // 1024*1024
    float* ssum = sr   + (size_t)NN * NN;     // 1024*1024

    k_main<<<GRUB + RELB, NTH, 0, stream>>>(x, rel, W, fc_w,
                                            Wih0, Whh0, bih0, bhh0,
                                            Wih1, Whh1, bih1, bhh1,
                                            sa, sb, hdot, hb, sr, ssum);
    k2<<<NN, 256, 0, stream>>>(sa, sb, hdot, hb, sr, ssum,
                               b, fc_b, (float*)d_out);
}

// Round 12
// 436.023 us; speedup vs baseline: 1.3699x; 1.3699x over previous
//
#include <hip/hip_runtime.h>
#include <cstddef>

#define NN 1024
#define DD 6
#define TT 60
#define HH 64
#define NEGV  (-10000.0f)
#define SLOPEV (0.01f)
#define GRUB 64           // GRU blocks: 16 samples each, 4 waves
#define RELB 896          // rel streaming blocks

// LDS float offsets (stride-19 pads on f32 tiles; f16 areas byte-managed)
#define PRZ 0             // [row 0..127][19]  r,z preacts
#define PXN 2432          // [row 0..63][19]   xn preacts
#define PHN 3648          // [row 0..63][19]   hn preacts
#define HF0 4864          // h0 f32 [j][19]
#define HF1 6080          // h1 f32 [j][19]
#define BH0 7296          // h0 f16 [n][72]  (576 f32)
#define BH1 7872          // h1 f16 [n][72]
#define XH  8448          // x f16 [(t*16+n)*8 + d] (3840 f32)
#define SMEMF 12288       // 48 KB

typedef _Float16 v8h __attribute__((ext_vector_type(8)));
typedef float    v4f __attribute__((ext_vector_type(4)));

#define MF(a, b, c) __builtin_amdgcn_mfma_f32_16x16x32_f16((a), (b), (c), 0, 0, 0)

__device__ __forceinline__ float sig_(float x)  { return 1.0f / (1.0f + __expf(-x)); }
__device__ __forceinline__ float tanh_(float x) { return 1.0f - 2.0f / (__expf(2.0f * x) + 1.0f); }
__device__ __forceinline__ float bcf_(const float a, const float b) {
    return __builtin_bit_cast(float, __builtin_amdgcn_cvt_pkrtz(a, b));
}
__device__ __forceinline__ v8h zero8() {
    v8h r;
    #pragma unroll
    for (int j = 0; j < 8; ++j) r[j] = (_Float16)0.f;
    return r;
}
__device__ __forceinline__ v8h pack8(const float* __restrict__ p) {
    v8h r;
    #pragma unroll
    for (int j = 0; j < 8; ++j) r[j] = (_Float16)p[j];
    return r;
}
__device__ __forceinline__ v8h pack6(const float* __restrict__ p) {
    v8h r = zero8();
    #pragma unroll
    for (int j = 0; j < 6; ++j) r[j] = (_Float16)p[j];
    return r;
}

// ---------------------------------------------------------------------------
// k_main: blocks [0,64) = MFMA-batched GRU (16 samples, 4 waves);
//         blocks [64,960) = rel streaming (LDS-free, scalar Wv).
// GRU: per step, 4 barrier-separated phases:
//   A: L0 MM  — 12 row-tiles of [Whh0|Wih0](192x96)·[h0;x_t](96x16) via
//      3 mfma/tile (n-gate split: hn 2 mfma + xn 1 mfma, separate C).
//   B: L0 update — 1024 h-elems / 256 thr, writes Hf0 f32 + Bh0 f16.
//   C: L1 MM  — [Wih1|Whh1](192x128)·[h0_cur;h1_prev] via 4 mfma/tile.
//   D: L1 update — writes Hf1 f32 + Bh1 f16.
// Weights = persistent A-fragments in registers (no readlane MM — R8-R11's
// ~128 readlane->fdot2 hazard pairs/wave/step were the ~250us floor).
// ---------------------------------------------------------------------------
__global__ __launch_bounds__(256, 1)
void k_main(const float* __restrict__ x, const float* __restrict__ rel,
            const float* __restrict__ W, const float* __restrict__ fc_w,
            const float* __restrict__ Wih0, const float* __restrict__ Whh0,
            const float* __restrict__ bih0, const float* __restrict__ bhh0,
            const float* __restrict__ Wih1, const float* __restrict__ Whh1,
            const float* __restrict__ bih1, const float* __restrict__ bhh1,
            float* __restrict__ sa, float* __restrict__ sb,
            float* __restrict__ hdot, float* __restrict__ hb,
            float* __restrict__ sr, float* __restrict__ ssum)
{
    __shared__ float smem[SMEMF];
    const int tid = threadIdx.x;

    if (blockIdx.x >= GRUB) {
        // ---------------- relation streaming (no LDS, no barriers) ----------
        const float* __restrict__ Wv = W + 2 * HH;     // uniform -> s_loads
        const unsigned base = (unsigned)(blockIdx.x - GRUB) * 256 + tid;
        for (unsigned p = base; p < (unsigned)(NN * NN); p += (unsigned)RELB * 256) {
            const float4* b4 = (const float4*)(rel + (size_t)p * 64);
            float4 v[16];
            #pragma unroll
            for (int q = 0; q < 16; ++q) v[q] = b4[q];
            float d0 = 0.f, d1 = 0.f, s0 = 0.f, s1 = 0.f;
            #pragma unroll
            for (int q = 0; q < 16; ++q) {
                d0 += v[q].x * Wv[4*q]   + v[q].z * Wv[4*q+2];
                d1 += v[q].y * Wv[4*q+1] + v[q].w * Wv[4*q+3];
                s0 += v[q].x + v[q].z;
                s1 += v[q].y + v[q].w;
            }
            sr[p]   = d0 + d1;
            ssum[p] = s0 + s1;
        }
        return;
    }

    // ---------------- GRU ----------------
    const int w    = tid >> 6;          // wave 0..3 (row-tile group)
    const int lane = tid & 63;
    const int quad = lane >> 4;
    const int mc   = lane & 15;         // A-m / B-n / C-col
    const int nb   = blockIdx.x * 16;

    // ---- stage x as f16 [(t,n) -> 8 slots, 2 zero] ----
    for (int idx = tid; idx < TT * 16; idx += 256) {
        const int t = idx >> 4, n = idx & 15;
        const float* xp = x + (size_t)(nb + n) * (DD * TT) + t;
        float4 pk;
        pk.x = bcf_(xp[0],   xp[60]);
        pk.y = bcf_(xp[120], xp[180]);
        pk.z = bcf_(xp[240], xp[300]);
        pk.w = 0.f;
        *(float4*)(smem + XH + idx * 4) = pk;
    }
    for (int idx = tid; idx < 1152; idx += 256) smem[BH0 + idx] = 0.f;  // Bh0+Bh1
    for (int idx = tid; idx < 2432; idx += 256) smem[HF0 + idx] = 0.f;  // Hf0+Hf1

    // ---- persistent A-fragments (f16 weights in registers) ----
    const int r0row = 16 * w + mc;
    const int zrow  = 64 + 16 * w + mc;
    const int nrow  = 128 + 16 * w + mc;
    const v8h Ar0 = pack8(Whh0 + (size_t)r0row * HH + quad * 8);
    const v8h Ar1 = pack8(Whh0 + (size_t)r0row * HH + 32 + quad * 8);
    const v8h Az0 = pack8(Whh0 + (size_t)zrow  * HH + quad * 8);
    const v8h Az1 = pack8(Whh0 + (size_t)zrow  * HH + 32 + quad * 8);
    const v8h An0 = pack8(Whh0 + (size_t)nrow  * HH + quad * 8);
    const v8h An1 = pack8(Whh0 + (size_t)nrow  * HH + 32 + quad * 8);
    v8h Arx = zero8(), Azx = zero8(), Anx = zero8();
    if (quad == 0) {
        Arx = pack6(Wih0 + r0row * DD);
        Azx = pack6(Wih0 + zrow  * DD);
        Anx = pack6(Wih0 + nrow  * DD);
    }
    const v8h R0 = pack8(Wih1 + (size_t)r0row * HH + quad * 8);
    const v8h R1 = pack8(Wih1 + (size_t)r0row * HH + 32 + quad * 8);
    const v8h R2 = pack8(Whh1 + (size_t)r0row * HH + quad * 8);
    const v8h R3 = pack8(Whh1 + (size_t)r0row * HH + 32 + quad * 8);
    const v8h Z0 = pack8(Wih1 + (size_t)zrow * HH + quad * 8);
    const v8h Z1 = pack8(Wih1 + (size_t)zrow * HH + 32 + quad * 8);
    const v8h Z2 = pack8(Whh1 + (size_t)zrow * HH + quad * 8);
    const v8h Z3 = pack8(Whh1 + (size_t)zrow * HH + 32 + quad * 8);
    const v8h Nx0 = pack8(Wih1 + (size_t)nrow * HH + quad * 8);
    const v8h Nx1 = pack8(Wih1 + (size_t)nrow * HH + 32 + quad * 8);
    const v8h Nh0 = pack8(Whh1 + (size_t)nrow * HH + quad * 8);
    const v8h Nh1 = pack8(Whh1 + (size_t)nrow * HH + 32 + quad * 8);

    // ---- biases at C rows (row = tile_base + quad*4 + e) ----
    float bR0[4], bZ0v[4], bXn0[4], bHn0[4], bR1[4], bZ1v[4], bXn1[4], bHn1[4];
    #pragma unroll
    for (int e = 0; e < 4; ++e) {
        const int cr = 16 * w + quad * 4 + e;
        bR0[e]  = bih0[cr] + bhh0[cr];
        bZ0v[e] = bih0[64 + cr] + bhh0[64 + cr];
        bXn0[e] = bih0[128 + cr];
        bHn0[e] = bhh0[128 + cr];
        bR1[e]  = bih1[cr] + bhh1[cr];
        bZ1v[e] = bih1[64 + cr] + bhh1[64 + cr];
        bXn1[e] = bih1[128 + cr];
        bHn1[e] = bhh1[128 + cr];
    }
    __syncthreads();

    auto ldb = [&](int BH, int win) -> v8h {
        return __builtin_bit_cast(v8h,
            *(const float4*)(smem + BH + mc * 36 + win * 16 + quad * 4));
    };
    auto stC = [&](int base, int rowbase, v4f c) {
        #pragma unroll
        for (int e = 0; e < 4; ++e)
            smem[base + (rowbase + quad * 4 + e) * 19 + mc] = c[e];
    };
    auto upd = [&](int HF, int BH) {
        const int n = tid & 15, jb = (tid >> 4) * 4;
        float hv[4];
        #pragma unroll
        for (int e = 0; e < 4; ++e) {
            const int j = jb + e;
            const float rp = smem[PRZ + j * 19 + n];
            const float zp = smem[PRZ + (64 + j) * 19 + n];
            const float xn = smem[PXN + j * 19 + n];
            const float hn = smem[PHN + j * 19 + n];
            const float hp = smem[HF + j * 19 + n];
            const float r  = sig_(rp), z = sig_(zp);
            const float nv = tanh_(xn + r * hn);
            const float h  = (1.f - z) * nv + z * hp;
            smem[HF + j * 19 + n] = h;
            hv[e] = h;
        }
        float2 pk;
        pk.x = bcf_(hv[0], hv[1]);
        pk.y = bcf_(hv[2], hv[3]);
        *(float2*)(smem + BH + n * 36 + (jb >> 1)) = pk;
    };

    for (int t = 0; t < TT; ++t) {
        // ---------------- phase A: L0 MM ----------------
        {
            const v8h b0 = ldb(BH0, 0);
            const v8h b1 = ldb(BH0, 1);
            const float4 xl = *(const float4*)(smem + XH + (t * 16 + mc) * 4);
            v8h bx = zero8();
            if (quad == 0) bx = __builtin_bit_cast(v8h, xl);

            v4f c = {bR0[0], bR0[1], bR0[2], bR0[3]};
            c = MF(Ar0, b0, c); c = MF(Ar1, b1, c); c = MF(Arx, bx, c);
            stC(PRZ, 16 * w, c);
            v4f cz = {bZ0v[0], bZ0v[1], bZ0v[2], bZ0v[3]};
            cz = MF(Az0, b0, cz); cz = MF(Az1, b1, cz); cz = MF(Azx, bx, cz);
            stC(PRZ, 64 + 16 * w, cz);
            v4f ch = {bHn0[0], bHn0[1], bHn0[2], bHn0[3]};
            ch = MF(An0, b0, ch); ch = MF(An1, b1, ch);
            stC(PHN, 16 * w, ch);
            v4f cx = {bXn0[0], bXn0[1], bXn0[2], bXn0[3]};
            cx = MF(Anx, bx, cx);
            stC(PXN, 16 * w, cx);
        }
        __syncthreads();
        upd(HF0, BH0);                         // phase B: h0 <- t
        __syncthreads();
        // ---------------- phase C: L1 MM ----------------
        {
            const v8h g0 = ldb(BH0, 0);        // h0 current
            const v8h g1 = ldb(BH0, 1);
            const v8h g2 = ldb(BH1, 0);        // h1 previous
            const v8h g3 = ldb(BH1, 1);

            v4f c = {bR1[0], bR1[1], bR1[2], bR1[3]};
            c = MF(R0, g0, c); c = MF(R1, g1, c); c = MF(R2, g2, c); c = MF(R3, g3, c);
            stC(PRZ, 16 * w, c);
            v4f cz = {bZ1v[0], bZ1v[1], bZ1v[2], bZ1v[3]};
            cz = MF(Z0, g0, cz); cz = MF(Z1, g1, cz); cz = MF(Z2, g2, cz); cz = MF(Z3, g3, cz);
            stC(PRZ, 64 + 16 * w, cz);
            v4f cx = {bXn1[0], bXn1[1], bXn1[2], bXn1[3]};
            cx = MF(Nx0, g0, cx); cx = MF(Nx1, g1, cx);
            stC(PXN, 16 * w, cx);
            v4f ch = {bHn1[0], bHn1[1], bHn1[2], bHn1[3]};
            ch = MF(Nh0, g2, ch); ch = MF(Nh1, g3, ch);
            stC(PHN, 16 * w, ch);
        }
        __syncthreads();
        upd(HF1, BH1);                         // phase D: h1 <- t
        __syncthreads();
    }

    // ---------------- epilogue: 4 scalars x 16 samples ----------------
    {
        const int n = lane >> 2, p = lane & 3;
        const float* __restrict__ wp = (w == 0) ? W : (w == 1) ? (W + HH)
                                     : (w == 2) ? fc_w : (fc_w + HH);
        float v = 0.f;
        #pragma unroll
        for (int q = 0; q < 16; ++q) {
            const int j = p * 16 + q;
            v += smem[HF1 + j * 19 + n] * wp[j];
        }
        v += __shfl_down(v, 2);
        v += __shfl_down(v, 1);
        if (p == 0) {
            float* dst = (w == 0) ? sa : (w == 1) ? sb : (w == 2) ? hdot : hb;
            dst[nb + n] = v;
        }
    }
}

// ---------------------------------------------------------------------------
// k2: per row i — masked leaky scores, exact masked-softmax semantics,
// out_i = hdot_i + (sum_j e_j*m_j*hb_j)/denom + fc_b.   (verified R2-R11)
// ---------------------------------------------------------------------------
__global__ __launch_bounds__(256)
void k2(const float* __restrict__ sa, const float* __restrict__ sb,
        const float* __restrict__ hdot, const float* __restrict__ hb,
        const float* __restrict__ sr, const float* __restrict__ ssum,
        const float* __restrict__ bscal, const float* __restrict__ fc_b,
        float* __restrict__ out)
{
    __shared__ float red[12];
    const int i   = blockIdx.x;
    const int tid = threadIdx.x;
    const int j4  = tid * 4;
    const float sai = sa[i] + bscal[0];

    const float4 srv = *(const float4*)(sr   + (size_t)i * NN + j4);
    const float4 ssv = *(const float4*)(ssum + (size_t)i * NN + j4);
    const float4 sbv = *(const float4*)(sb + j4);

    float tv[4], mk[4];
    float mloc = -3.4e38f;
    {
        const float srq[4] = {srv.x, srv.y, srv.z, srv.w};
        const float ssq[4] = {ssv.x, ssv.y, ssv.z, ssv.w};
        const float sbq[4] = {sbv.x, sbv.y, sbv.z, sbv.w};
        #pragma unroll
        for (int q = 0; q < 4; ++q) {
            float wv = sai + sbq[q] + srq[q];
            wv = (wv >= 0.0f) ? wv : SLOPEV * wv;
            const float m = (ssq[q] != 0.0f) ? 1.0f : 0.0f;
            float tt = m * wv;
            tt = (tt == 0.0f) ? NEGV : tt;
            tv[q] = tt; mk[q] = m;
            mloc = fmaxf(mloc, tt);
        }
    }
    #pragma unroll
    for (int off = 32; off >= 1; off >>= 1) mloc = fmaxf(mloc, __shfl_xor(mloc, off));
    if ((tid & 63) == 0) red[tid >> 6] = mloc;
    __syncthreads();
    const float mx = fmaxf(fmaxf(red[0], red[1]), fmaxf(red[2], red[3]));

    const float4 hbv = *(const float4*)(hb + j4);
    const float hbq[4] = {hbv.x, hbv.y, hbv.z, hbv.w};
    float sloc = 0.0f, vloc = 0.0f;
    #pragma unroll
    for (int q = 0; q < 4; ++q) {
        const float e = __expf(tv[q] - mx);   // masked -> exp(-1e4 - mx) == 0
        sloc += e;
        vloc += e * mk[q] * hbq[q];
    }
    #pragma unroll
    for (int off = 32; off >= 1; off >>= 1) {
        sloc += __shfl_xor(sloc, off);
        vloc += __shfl_xor(vloc, off);
    }
    if ((tid & 63) == 0) { red[4 + (tid >> 6)] = sloc; red[8 + (tid >> 6)] = vloc; }
    __syncthreads();
    if (tid == 0) {
        const float denom = red[4] + red[5] + red[6] + red[7];
        const float vsum  = red[8] + red[9] + red[10] + red[11];
        out[i] = hdot[i] + vsum / denom + fc_b[0];
    }
}

// ---------------------------------------------------------------------------
extern "C" void kernel_launch(void* const* d_in, const int* in_sizes, int n_in,
                              void* d_out, int out_size, void* d_ws, size_t ws_size,
                              hipStream_t stream)
{
    const float* x     = (const float*)d_in[0];
    const float* rel   = (const float*)d_in[1];
    const float* W     = (const float*)d_in[2];
    const float* b     = (const float*)d_in[3];
    const float* fc_w  = (const float*)d_in[4];
    const float* fc_b  = (const float*)d_in[5];
    const float* Wih0  = (const float*)d_in[6];
    const float* Whh0  = (const float*)d_in[7];
    const float* bih0  = (const float*)d_in[8];
    const float* bhh0  = (const float*)d_in[9];
    const float* Wih1  = (const float*)d_in[10];
    const float* Whh1  = (const float*)d_in[11];
    const float* bih1  = (const float*)d_in[12];
    const float* bhh1  = (const float*)d_in[13];

    float* ws   = (float*)d_ws;
    float* sa   = ws;                         // 1024
    float* sb   = sa   + NN;                  // 1024
    float* hdot = sb   + NN;                  // 1024
    float* hb   = hdot + NN;                  // 1024
    float* sr   = hb   + NN;                  // 1024*1024
    float* ssum = sr   + (size_t)NN * NN;     // 1024*1024

    k_main<<<GRUB + RELB, 256, 0, stream>>>(x, rel, W, fc_w,
                                            Wih0, Whh0, bih0, bhh0,
                                            Wih1, Whh1, bih1, bhh1,
                                            sa, sb, hdot, hb, sr, ssum);
    k2<<<NN, 256, 0, stream>>>(sa, sb, hdot, hb, sr, ssum,
                               b, fc_b, (float*)d_out);
}

// Round 13
// 386.744 us; speedup vs baseline: 1.5444x; 1.1274x over previous
//
#include <hip/hip_runtime.h>
#include <cstddef>

#define NN 1024
#define DD 6
#define TT 60
#define HH 64
#define NEGV  (-10000.0f)
#define SLOPEV (0.01f)
#define GRUB 64           // GRU blocks: 16 samples, 8 waves (512 thr)
#define RELB 896          // rel streaming blocks

// LDS float offsets
#define PA_RZ 0           // L0 r,z preacts [row 0..127][19]
#define PA_XN 2432        // L0 xn [row 0..63][19]
#define PA_HN 3648        // L0 hn
#define PB_RZ 4864        // L1 r,z preacts
#define PB_XN 7296        // L1 xn
#define PB_HN 8512        // L1 hn
#define HF0   9728        // h0 f32 [j][19]
#define HF1   10944       // h1 f32 [j][19]
#define BH0   12160       // h0 f16 [n][72]
#define BH1   12736       // h1 f16 [n][72]
#define XH    13312       // x f16 [(t*16+n)*8]
#define SMEMF 17152       // 68.6 KB -> 2 blocks/CU

typedef _Float16 v8h __attribute__((ext_vector_type(8)));
typedef float    v4f __attribute__((ext_vector_type(4)));

#define MF(a, b, c) __builtin_amdgcn_mfma_f32_16x16x32_f16((a), (b), (c), 0, 0, 0)

__device__ __forceinline__ float sig_(float x)  { return 1.0f / (1.0f + __expf(-x)); }
__device__ __forceinline__ float tanh_(float x) { return 1.0f - 2.0f / (__expf(2.0f * x) + 1.0f); }
__device__ __forceinline__ float bcf_(const float a, const float b) {
    return __builtin_bit_cast(float, __builtin_amdgcn_cvt_pkrtz(a, b));
}
__device__ __forceinline__ v8h zero8() {
    v8h r;
    #pragma unroll
    for (int j = 0; j < 8; ++j) r[j] = (_Float16)0.f;
    return r;
}
__device__ __forceinline__ v8h pack8(const float* __restrict__ p) {
    v8h r;
    #pragma unroll
    for (int j = 0; j < 8; ++j) r[j] = (_Float16)p[j];
    return r;
}
__device__ __forceinline__ v8h pack6(const float* __restrict__ p) {
    v8h r = zero8();
    #pragma unroll
    for (int j = 0; j < 6; ++j) r[j] = (_Float16)p[j];
    return r;
}

// ---------------------------------------------------------------------------
// k_main: blocks [0,64) = MFMA GRU, 16 samples, 8 waves, software-pipelined:
//   MM phase : waves 0-3 = ALL L0 tiles for t=i (9 mfma/wave);
//              waves 4-7 = ALL L1 tiles for t=i-1 (12 mfma/wave).
//   UPD phase: thr 0-255 update h0(t=i); thr 256-511 update h1(t=i-1).
//   => 2 barriers/step (R12 had 4 + only 4 waves: latency-bound 7k cyc/step).
// 68.6 KB LDS -> 2 blocks/CU: each GRU block co-resides with a rel block
// whose HBM stalls fill the GRU's barrier gaps.
// blocks [64,960) = rel streaming (scalar Wv, no barriers).
// ---------------------------------------------------------------------------
__global__ __launch_bounds__(512)
void k_main(const float* __restrict__ x, const float* __restrict__ rel,
            const float* __restrict__ W, const float* __restrict__ fc_w,
            const float* __restrict__ Wih0, const float* __restrict__ Whh0,
            const float* __restrict__ bih0, const float* __restrict__ bhh0,
            const float* __restrict__ Wih1, const float* __restrict__ Whh1,
            const float* __restrict__ bih1, const float* __restrict__ bhh1,
            float* __restrict__ sa, float* __restrict__ sb,
            float* __restrict__ hdot, float* __restrict__ hb,
            float* __restrict__ sr, float* __restrict__ ssum)
{
    __shared__ float smem[SMEMF];
    const int tid = threadIdx.x;

    if (blockIdx.x >= GRUB) {
        // ---------------- relation streaming ----------------
        const float* __restrict__ Wv = W + 2 * HH;     // uniform -> s_loads
        const unsigned base = (unsigned)(blockIdx.x - GRUB) * 512 + tid;
        for (unsigned p = base; p < (unsigned)(NN * NN); p += (unsigned)RELB * 512) {
            const float4* b4 = (const float4*)(rel + (size_t)p * 64);
            float4 v[16];
            #pragma unroll
            for (int q = 0; q < 16; ++q) v[q] = b4[q];
            float d0 = 0.f, d1 = 0.f, s0 = 0.f, s1 = 0.f;
            #pragma unroll
            for (int q = 0; q < 16; ++q) {
                d0 += v[q].x * Wv[4*q]   + v[q].z * Wv[4*q+2];
                d1 += v[q].y * Wv[4*q+1] + v[q].w * Wv[4*q+3];
                s0 += v[q].x + v[q].z;
                s1 += v[q].y + v[q].w;
            }
            sr[p]   = d0 + d1;
            ssum[p] = s0 + s1;
        }
        return;
    }

    // ---------------- GRU ----------------
    const int w    = tid >> 6;          // wave 0..7
    const int lane = tid & 63;
    const int quad = lane >> 4;
    const int mc   = lane & 15;
    const int nb   = blockIdx.x * 16;
    const bool isL0 = (w < 4);
    const int wt   = isL0 ? w : (w - 4);   // row-tile index within layer

    // ---- stage x as f16 ----
    for (int idx = tid; idx < TT * 16; idx += 512) {
        const int t = idx >> 4, n = idx & 15;
        const float* xp = x + (size_t)(nb + n) * (DD * TT) + t;
        float4 pk;
        pk.x = bcf_(xp[0],   xp[60]);
        pk.y = bcf_(xp[120], xp[180]);
        pk.z = bcf_(xp[240], xp[300]);
        pk.w = 0.f;
        *(float4*)(smem + XH + idx * 4) = pk;
    }
    for (int idx = tid; idx < 1152; idx += 512) smem[BH0 + idx] = 0.f;
    for (int idx = tid; idx < 2432; idx += 512) smem[HF0 + idx] = 0.f;

    // ---- per-role persistent A-fragments ----
    const int r0row = 16 * wt + mc;
    const int zrow  = 64 + 16 * wt + mc;
    const int nrow  = 128 + 16 * wt + mc;
    v8h F0 = zero8(), F1 = zero8(), F2 = zero8(), F3 = zero8();
    v8h F4 = zero8(), F5 = zero8(), F6 = zero8(), F7 = zero8();
    v8h F8 = zero8(), F9 = zero8(), F10 = zero8(), F11 = zero8();
    v8h Xr = zero8(), Xz = zero8(), Xn = zero8();
    if (isL0) {
        F0 = pack8(Whh0 + (size_t)r0row * HH + quad * 8);         // Ar0
        F1 = pack8(Whh0 + (size_t)r0row * HH + 32 + quad * 8);    // Ar1
        F2 = pack8(Whh0 + (size_t)zrow  * HH + quad * 8);         // Az0
        F3 = pack8(Whh0 + (size_t)zrow  * HH + 32 + quad * 8);    // Az1
        F4 = pack8(Whh0 + (size_t)nrow  * HH + quad * 8);         // An0
        F5 = pack8(Whh0 + (size_t)nrow  * HH + 32 + quad * 8);    // An1
        if (quad == 0) {
            Xr = pack6(Wih0 + r0row * DD);
            Xz = pack6(Wih0 + zrow  * DD);
            Xn = pack6(Wih0 + nrow  * DD);
        }
    } else {
        F0 = pack8(Wih1 + (size_t)r0row * HH + quad * 8);         // R0
        F1 = pack8(Wih1 + (size_t)r0row * HH + 32 + quad * 8);    // R1
        F2 = pack8(Whh1 + (size_t)r0row * HH + quad * 8);         // R2
        F3 = pack8(Whh1 + (size_t)r0row * HH + 32 + quad * 8);    // R3
        F4 = pack8(Wih1 + (size_t)zrow * HH + quad * 8);          // Z0
        F5 = pack8(Wih1 + (size_t)zrow * HH + 32 + quad * 8);     // Z1
        F6 = pack8(Whh1 + (size_t)zrow * HH + quad * 8);          // Z2
        F7 = pack8(Whh1 + (size_t)zrow * HH + 32 + quad * 8);     // Z3
        F8 = pack8(Wih1 + (size_t)nrow * HH + quad * 8);          // Nx0
        F9 = pack8(Wih1 + (size_t)nrow * HH + 32 + quad * 8);     // Nx1
        F10 = pack8(Whh1 + (size_t)nrow * HH + quad * 8);         // Nh0
        F11 = pack8(Whh1 + (size_t)nrow * HH + 32 + quad * 8);    // Nh1
    }

    // ---- biases at C rows ----
    float bR[4], bZ[4], bXn[4], bHn[4];
    #pragma unroll
    for (int e = 0; e < 4; ++e) {
        const int cr = 16 * wt + quad * 4 + e;
        if (isL0) {
            bR[e]  = bih0[cr] + bhh0[cr];
            bZ[e]  = bih0[64 + cr] + bhh0[64 + cr];
            bXn[e] = bih0[128 + cr];
            bHn[e] = bhh0[128 + cr];
        } else {
            bR[e]  = bih1[cr] + bhh1[cr];
            bZ[e]  = bih1[64 + cr] + bhh1[64 + cr];
            bXn[e] = bih1[128 + cr];
            bHn[e] = bhh1[128 + cr];
        }
    }
    __syncthreads();

    auto ldb = [&](int BH, int win) -> v8h {
        return __builtin_bit_cast(v8h,
            *(const float4*)(smem + BH + mc * 36 + win * 16 + quad * 4));
    };
    auto stC = [&](int base, int rowbase, v4f c) {
        #pragma unroll
        for (int e = 0; e < 4; ++e)
            smem[base + (rowbase + quad * 4 + e) * 19 + mc] = c[e];
    };
    auto upd = [&](int PRZ, int PXN, int PHN, int HF, int BH, int lt) {
        const int n = lt & 15, jb = (lt >> 4) * 4;
        float hv[4];
        #pragma unroll
        for (int e = 0; e < 4; ++e) {
            const int j = jb + e;
            const float rp = smem[PRZ + j * 19 + n];
            const float zp = smem[PRZ + (64 + j) * 19 + n];
            const float xn = smem[PXN + j * 19 + n];
            const float hn = smem[PHN + j * 19 + n];
            const float hp = smem[HF + j * 19 + n];
            const float r  = sig_(rp), z = sig_(zp);
            const float nv = tanh_(xn + r * hn);
            const float h  = (1.f - z) * nv + z * hp;
            smem[HF + j * 19 + n] = h;
            hv[e] = h;
        }
        float2 pk;
        pk.x = bcf_(hv[0], hv[1]);
        pk.y = bcf_(hv[2], hv[3]);
        *(float2*)(smem + BH + n * 36 + (jb >> 1)) = pk;
    };

    for (int i = 0; i <= TT; ++i) {
        // ---------------- MM phase (L0 for t=i, L1 for t=i-1) ----------------
        if (isL0) {
            if (i < TT) {
                const v8h b0 = ldb(BH0, 0);
                const v8h b1 = ldb(BH0, 1);
                const float4 xl = *(const float4*)(smem + XH + (i * 16 + mc) * 4);
                v8h bx = zero8();
                if (quad == 0) bx = __builtin_bit_cast(v8h, xl);

                v4f c = {bR[0], bR[1], bR[2], bR[3]};
                c = MF(F0, b0, c); c = MF(F1, b1, c); c = MF(Xr, bx, c);
                stC(PA_RZ, 16 * wt, c);
                v4f cz = {bZ[0], bZ[1], bZ[2], bZ[3]};
                cz = MF(F2, b0, cz); cz = MF(F3, b1, cz); cz = MF(Xz, bx, cz);
                stC(PA_RZ, 64 + 16 * wt, cz);
                v4f ch = {bHn[0], bHn[1], bHn[2], bHn[3]};
                ch = MF(F4, b0, ch); ch = MF(F5, b1, ch);
                stC(PA_HN, 16 * wt, ch);
                v4f cx = {bXn[0], bXn[1], bXn[2], bXn[3]};
                cx = MF(Xn, bx, cx);
                stC(PA_XN, 16 * wt, cx);
            }
        } else {
            if (i >= 1) {
                const v8h g0 = ldb(BH0, 0);        // h0 after t=i-1
                const v8h g1 = ldb(BH0, 1);
                const v8h g2 = ldb(BH1, 0);        // h1 after t=i-2
                const v8h g3 = ldb(BH1, 1);

                v4f c = {bR[0], bR[1], bR[2], bR[3]};
                c = MF(F0, g0, c); c = MF(F1, g1, c); c = MF(F2, g2, c); c = MF(F3, g3, c);
                stC(PB_RZ, 16 * wt, c);
                v4f cz = {bZ[0], bZ[1], bZ[2], bZ[3]};
                cz = MF(F4, g0, cz); cz = MF(F5, g1, cz); cz = MF(F6, g2, cz); cz = MF(F7, g3, cz);
                stC(PB_RZ, 64 + 16 * wt, cz);
                v4f cx = {bXn[0], bXn[1], bXn[2], bXn[3]};
                cx = MF(F8, g0, cx); cx = MF(F9, g1, cx);
                stC(PB_XN, 16 * wt, cx);
                v4f ch = {bHn[0], bHn[1], bHn[2], bHn[3]};
                ch = MF(F10, g2, ch); ch = MF(F11, g3, ch);
                stC(PB_HN, 16 * wt, ch);
            }
        }
        __syncthreads();
        // ---------------- UPD phase ----------------
        if (tid < 256) {
            if (i < TT) upd(PA_RZ, PA_XN, PA_HN, HF0, BH0, tid);
        } else {
            if (i >= 1) upd(PB_RZ, PB_XN, PB_HN, HF1, BH1, tid - 256);
        }
        __syncthreads();
    }

    // ---------------- epilogue: 4 scalars x 16 samples (waves 0-3) ----------
    if (w < 4) {
        const int n = lane >> 2, p = lane & 3;
        const float* __restrict__ wp = (w == 0) ? W : (w == 1) ? (W + HH)
                                     : (w == 2) ? fc_w : (fc_w + HH);
        float v = 0.f;
        #pragma unroll
        for (int q = 0; q < 16; ++q) {
            const int j = p * 16 + q;
            v += smem[HF1 + j * 19 + n] * wp[j];
        }
        v += __shfl_down(v, 2);
        v += __shfl_down(v, 1);
        if (p == 0) {
            float* dst = (w == 0) ? sa : (w == 1) ? sb : (w == 2) ? hdot : hb;
            dst[nb + n] = v;
        }
    }
}

// ---------------------------------------------------------------------------
// k2: per row i — masked leaky scores, exact masked-softmax semantics,
// out_i = hdot_i + (sum_j e_j*m_j*hb_j)/denom + fc_b.   (verified R2-R12)
// ---------------------------------------------------------------------------
__global__ __launch_bounds__(256)
void k2(const float* __restrict__ sa, const float* __restrict__ sb,
        const float* __restrict__ hdot, const float* __restrict__ hb,
        const float* __restrict__ sr, const float* __restrict__ ssum,
        const float* __restrict__ bscal, const float* __restrict__ fc_b,
        float* __restrict__ out)
{
    __shared__ float red[12];
    const int i   = blockIdx.x;
    const int tid = threadIdx.x;
    const int j4  = tid * 4;
    const float sai = sa[i] + bscal[0];

    const float4 srv = *(const float4*)(sr   + (size_t)i * NN + j4);
    const float4 ssv = *(const float4*)(ssum + (size_t)i * NN + j4);
    const float4 sbv = *(const float4*)(sb + j4);

    float tv[4], mk[4];
    float mloc = -3.4e38f;
    {
        const float srq[4] = {srv.x, srv.y, srv.z, srv.w};
        const float ssq[4] = {ssv.x, ssv.y, ssv.z, ssv.w};
        const float sbq[4] = {sbv.x, sbv.y, sbv.z, sbv.w};
        #pragma unroll
        for (int q = 0; q < 4; ++q) {
            float wv = sai + sbq[q] + srq[q];
            wv = (wv >= 0.0f) ? wv : SLOPEV * wv;
            const float m = (ssq[q] != 0.0f) ? 1.0f : 0.0f;
            float tt = m * wv;
            tt = (tt == 0.0f) ? NEGV : tt;
            tv[q] = tt; mk[q] = m;
            mloc = fmaxf(mloc, tt);
        }
    }
    #pragma unroll
    for (int off = 32; off >= 1; off >>= 1) mloc = fmaxf(mloc, __shfl_xor(mloc, off));
    if ((tid & 63) == 0) red[tid >> 6] = mloc;
    __syncthreads();
    const float mx = fmaxf(fmaxf(red[0], red[1]), fmaxf(red[2], red[3]));

    const float4 hbv = *(const float4*)(hb + j4);
    const float hbq[4] = {hbv.x, hbv.y, hbv.z, hbv.w};
    float sloc = 0.0f, vloc = 0.0f;
    #pragma unroll
    for (int q = 0; q < 4; ++q) {
        const float e = __expf(tv[q] - mx);   // masked -> exp(-1e4 - mx) == 0
        sloc += e;
        vloc += e * mk[q] * hbq[q];
    }
    #pragma unroll
    for (int off = 32; off >= 1; off >>= 1) {
        sloc += __shfl_xor(sloc, off);
        vloc += __shfl_xor(vloc, off);
    }
    if ((tid & 63) == 0) { red[4 + (tid >> 6)] = sloc; red[8 + (tid >> 6)] = vloc; }
    __syncthreads();
    if (tid == 0) {
        const float denom = red[4] + red[5] + red[6] + red[7];
        const float vsum  = red[8] + red[9] + red[10] + red[11];
        out[i] = hdot[i] + vsum / denom + fc_b[0];
    }
}

// ---------------------------------------------------------------------------
extern "C" void kernel_launch(void* const* d_in, const int* in_sizes, int n_in,
                              void* d_out, int out_size, void* d_ws, size_t ws_size,
                              hipStream_t stream)
{
    const float* x     = (const float*)d_in[0];
    const float* rel   = (const float*)d_in[1];
    const float* W     = (const float*)d_in[2];
    const float* b     = (const float*)d_in[3];
    const float* fc_w  = (const float*)d_in[4];
    const float* fc_b  = (const float*)d_in[5];
    const float* Wih0  = (const float*)d_in[6];
    const float* Whh0  = (const float*)d_in[7];
    const float* bih0  = (const float*)d_in[8];
    const float* bhh0  = (const float*)d_in[9];
    const float* Wih1  = (const float*)d_in[10];
    const float* Whh1  = (const float*)d_in[11];
    const float* bih1  = (const float*)d_in[12];
    const float* bhh1  = (const float*)d_in[13];

    float* ws   = (float*)d_ws;
    float* sa   = ws;                         // 1024
    float* sb   = sa   + NN;                  // 1024
    float* hdot = sb   + NN;                  // 1024
    float* hb   = hdot + NN;                  // 1024
    float* sr   = hb   + NN;                  // 1024*1024
    float* ssum = sr   + (size_t)NN * NN;     // 1024*1024

    k_main<<<GRUB + RELB, 512, 0, stream>>>(x, rel, W, fc_w,
                                            Wih0, Whh0, bih0, bhh0,
                                            Wih1, Whh1, bih1, bhh1,
                                            sa, sb, hdot, hb, sr, ssum);
    k2<<<NN, 256, 0, stream>>>(sa, sb, hdot, hb, sr, ssum,
                               b, fc_b, (float*)d_out);
}